// Round 6
// baseline (504.541 us; speedup 1.0000x reference)
//
#include <hip/hip_runtime.h>

// Problem constants (reference): B=64, N=256, S=16, HID=32, HEADS=8
#define NN 256
#define SS 16
#define HH 32
#define KK 8      // heads
#define NROWPAIRS 16384            // B*N (b,n) pairs
#define STATS_BLOCKS 2048

typedef float f32x4 __attribute__((ext_vector_type(4)));   // native vec for nt ld/st

// ---- workspace layout (bytes) ----
// 64    : uchar valid[16384]
// 16448 : int countPartial[2048]
// 24704 : float partials[2048][32]   (kind*16+s per block; 256 KB)
// 286848: float W1c[512]
// 288896: float b1c[32]
// No zeroing needed: all accumulators are written, never read-modify-written.

// ---------------------------------------------------------------------------
// Kernel 1: fused mask-dtype detect + valid[] + masked per-channel partial
// stats. Each block redundantly scans the first 16 KB of the mask region
// (L2-broadcast, ~1 us aggregate) -> no serial prep kernel. Block bid owns
// chunks {bid + k*2048 : k=0..7}; one (b,n) chunk = 256 rows x 16 ch = 16 KB.
// Partial sums go to partials[bid][0..31] (no atomics, no pre-zeroing).
// Reads are TEMPORAL on purpose: this pass populates L3 for the mlp re-read.
// ---------------------------------------------------------------------------
__global__ __launch_bounds__(256) void stats_kernel(
        const void* __restrict__ mask_raw,
        const float* __restrict__ stacks,
        unsigned char* __restrict__ valid,
        int* __restrict__ count_partial,
        float* __restrict__ partials) {
    int tid = threadIdx.x;
    int bid = blockIdx.x;

    __shared__ int s_flags[2];   // [0]=float pattern, [1]=bool pattern
    __shared__ int s_mode;
    __shared__ int s_count;
    __shared__ unsigned char s_valid[8];
    if (tid < 2) s_flags[tid] = 0;
    if (tid == 0) s_count = 0;
    __syncthreads();

    // Scan first 16384 bytes as 4096 words (in-bounds for all 3 layouts:
    // bool[16384] = 16KB exactly; int/float = 64KB).
    const unsigned int* w = (const unsigned int*)mask_raw;
    int f_float = 0, f_bool = 0;
    for (int i = tid; i < 4096; i += 256) {
        unsigned int v = w[i];
        if (v == 0x3F800000u) f_float = 1;
        // byte value 1 in a non-LSB position can only be packed bool bytes
        if (((v >> 8) & 0xFFu) == 1u || ((v >> 16) & 0xFFu) == 1u ||
            ((v >> 24) & 0xFFu) == 1u) f_bool = 1;
    }
    if (f_float) atomicOr(&s_flags[0], 1);
    if (f_bool)  atomicOr(&s_flags[1], 1);
    __syncthreads();
    if (tid == 0) s_mode = s_flags[1] ? 1 : (s_flags[0] ? 2 : 0);
    __syncthreads();
    int mode = s_mode;

    // valid bytes for this block's 8 chunks
    if (tid < 8) {
        int chunk = bid + tid * STATS_BLOCKS;
        int masked;
        if (mode == 1)      masked = ((const unsigned char*)mask_raw)[chunk] != 0;
        else if (mode == 2) masked = ((const float*)mask_raw)[chunk] != 0.0f;
        else                masked = ((const int*)mask_raw)[chunk] != 0;
        unsigned char v = (unsigned char)(masked ? 0 : 1);  // valid = !mask
        s_valid[tid] = v;
        valid[chunk] = v;
        if (v) atomicAdd(&s_count, 1);
    }
    __syncthreads();

    // masked sum / sum-of-squares; thread's float4 covers s = 4*(tid%4)..+3
    float4 s1 = make_float4(0.f, 0.f, 0.f, 0.f);
    float4 s2 = make_float4(0.f, 0.f, 0.f, 0.f);
    for (int k = 0; k < 8; ++k) {
        if (!s_valid[k]) continue;                 // block-uniform branch
        int chunk = bid + k * STATS_BLOCKS;
        const float4* p = (const float4*)stacks + (size_t)chunk * 1024;
        #pragma unroll
        for (int it = 0; it < 4; ++it) {
            float4 v = p[tid + it * 256];
            s1.x += v.x; s1.y += v.y; s1.z += v.z; s1.w += v.w;
            s2.x += v.x * v.x; s2.y += v.y * v.y;
            s2.z += v.z * v.z; s2.w += v.w * v.w;
        }
    }

    __shared__ float lds[8 * 256];   // [comp][tid]
    lds[0 * 256 + tid] = s1.x; lds[1 * 256 + tid] = s1.y;
    lds[2 * 256 + tid] = s1.z; lds[3 * 256 + tid] = s1.w;
    lds[4 * 256 + tid] = s2.x; lds[5 * 256 + tid] = s2.y;
    lds[6 * 256 + tid] = s2.z; lds[7 * 256 + tid] = s2.w;
    __syncthreads();

    if (tid < 32) {
        int kind = tid >> 4;          // 0 = sum, 1 = sum sq
        int s = tid & 15;
        int g = s >> 2, c = (s & 3) + kind * 4;
        float tot = 0.f;
        for (int i = 0; i < 64; ++i) tot += lds[c * 256 + (g + i * 4)];
        partials[bid * 32 + tid] = tot;          // plain store, no atomic
    }
    if (tid == 0) count_partial[bid] = s_count;
}

// ---------------------------------------------------------------------------
// Kernel 2: reduce the 2048 partials + counts, fold BN into layer 1.
// scale = gamma/sqrt(var+eps); shift = beta - mean*scale;
// W1c = scale (.) W1;  b1c = shift @ W1 + b1.   One block, 512 threads.
// ---------------------------------------------------------------------------
__global__ __launch_bounds__(512) void weights_kernel(
        const float* __restrict__ gamma,
        const float* __restrict__ beta,
        const float* __restrict__ W1,
        const float* __restrict__ b1,
        const float* __restrict__ partials,
        const int* __restrict__ count_partial,
        float* __restrict__ W1c,
        float* __restrict__ b1c) {
    int tid = threadIdx.x;
    __shared__ float red[512];
    __shared__ int s_cnt;
    __shared__ float s_scale[SS], s_shift[SS];

    if (tid == 0) s_cnt = 0;

    // sum partials: output c = tid&31, strip j = tid>>5 (16 strips of 128)
    {
        int c = tid & 31, j = tid >> 5;
        float acc = 0.f;
        for (int k = j; k < STATS_BLOCKS; k += 16) acc += partials[k * 32 + c];
        red[tid] = acc;
    }
    // sum counts: 4 per thread
    int cacc = 0;
    for (int k = tid; k < STATS_BLOCKS; k += 512) cacc += count_partial[k];
    __syncthreads();
    if (tid < 256) red[tid] += red[tid + 256];
    if (cacc) atomicAdd(&s_cnt, cacc);
    __syncthreads();
    if (tid < 128) red[tid] += red[tid + 128];
    __syncthreads();
    if (tid < 64) red[tid] += red[tid + 64];
    __syncthreads();
    if (tid < 32) red[tid] += red[tid + 32];
    __syncthreads();
    // red[s] = sum_x[s], red[16+s] = sum_x2[s]

    if (tid < SS) {
        float cnt = (float)s_cnt * (float)NN;
        if (cnt < 1.0f) cnt = 1.0f;
        float mean = red[tid] / cnt;
        float var  = red[16 + tid] / cnt - mean * mean;
        float sc   = gamma[tid] / sqrtf(var + 1e-5f);
        s_scale[tid] = sc;
        s_shift[tid] = beta[tid] - mean * sc;
    }
    __syncthreads();
    W1c[tid] = s_scale[tid >> 5] * W1[tid];
    if (tid < HH) {
        float acc = b1[tid];
        #pragma unroll
        for (int s = 0; s < SS; ++s) acc += s_shift[s] * W1[s * HH + tid];
        b1c[tid] = acc;
    }
}

// ---------------------------------------------------------------------------
// Kernel 3: per-row fused MLP. Block = one (b,n) chunk (mask branch is
// block-uniform); thread = one m row. 16 floats in, 8 floats out.
// Weights via uniform global loads (L1-served) — best-measured config.
//
// v6 L3-reuse: stats leaves L3 ordered by k-band recency (chunks
// 14336-16383 newest). mlp therefore walks chunks in REVERSE order,
// starting in the freshest band, and uses NONTEMPORAL loads for the
// stacks re-read (use-once data: hit if resident, don't allocate on miss,
// so it can't evict the older bands we haven't reached) and NONTEMPORAL
// stores for the output stream (don't pollute L3 at all).
// ---------------------------------------------------------------------------
__global__ __launch_bounds__(256) void mlp_kernel(
        const float* __restrict__ stacks,
        const unsigned char* __restrict__ valid,
        const float* __restrict__ W1c,
        const float* __restrict__ b1c,
        const float* __restrict__ W2,
        const float* __restrict__ b2,
        float* __restrict__ out) {
    int chunk = (NROWPAIRS - 1) - (int)blockIdx.x;   // reverse: newest L3 first
    int tid = threadIdx.x;
    size_t row = (size_t)chunk * NN + tid;
    f32x4* outp = (f32x4*)out + row * 2;

    if (!valid[chunk]) {
        f32x4 z = (f32x4){0.f, 0.f, 0.f, 0.f};
        __builtin_nontemporal_store(z, outp);
        __builtin_nontemporal_store(z, outp + 1);
        return;
    }

    const f32x4* xp = (const f32x4*)stacks + row * 4;
    f32x4 x0 = __builtin_nontemporal_load(xp);
    f32x4 x1 = __builtin_nontemporal_load(xp + 1);
    f32x4 x2 = __builtin_nontemporal_load(xp + 2);
    f32x4 x3 = __builtin_nontemporal_load(xp + 3);
    float x[SS] = { x0[0], x0[1], x0[2], x0[3],  x1[0], x1[1], x1[2], x1[3],
                    x2[0], x2[1], x2[2], x2[3],  x3[0], x3[1], x3[2], x3[3] };

    float h[HH];
    #pragma unroll
    for (int j = 0; j < HH; ++j) h[j] = b1c[j];
    #pragma unroll
    for (int k = 0; k < SS; ++k) {
        float xk = x[k];
        #pragma unroll
        for (int j = 0; j < HH; ++j) h[j] = fmaf(xk, W1c[k * HH + j], h[j]);
    }
    #pragma unroll
    for (int j = 0; j < HH; ++j) h[j] = fmaxf(h[j], 0.0f);

    float y[KK];
    #pragma unroll
    for (int i = 0; i < KK; ++i) y[i] = b2[i];
    #pragma unroll
    for (int j = 0; j < HH; ++j) {
        float hj = h[j];
        #pragma unroll
        for (int i = 0; i < KK; ++i) y[i] = fmaf(hj, W2[j * KK + i], y[i]);
    }

    f32x4 y0 = (f32x4){y[0], y[1], y[2], y[3]};
    f32x4 y1 = (f32x4){y[4], y[5], y[6], y[7]};
    __builtin_nontemporal_store(y0, outp);
    __builtin_nontemporal_store(y1, outp + 1);
}

extern "C" void kernel_launch(void* const* d_in, const int* in_sizes, int n_in,
                              void* d_out, int out_size, void* d_ws, size_t ws_size,
                              hipStream_t stream) {
    const float* stacks = (const float*)d_in[0];
    const void*  mask   = d_in[1];
    const float* gamma  = (const float*)d_in[2];
    const float* beta   = (const float*)d_in[3];
    const float* W1     = (const float*)d_in[4];
    const float* b1     = (const float*)d_in[5];
    const float* W2     = (const float*)d_in[6];
    const float* b2     = (const float*)d_in[7];
    float* out = (float*)d_out;

    char* ws = (char*)d_ws;
    unsigned char* valid        = (unsigned char*)(ws + 64);
    int*           countPartial = (int*)(ws + 16448);
    float*         partials     = (float*)(ws + 24704);
    float*         W1c          = (float*)(ws + 286848);
    float*         b1c          = (float*)(ws + 288896);

    stats_kernel<<<STATS_BLOCKS, 256, 0, stream>>>(mask, stacks, valid,
                                                   countPartial, partials);
    weights_kernel<<<1, 512, 0, stream>>>(gamma, beta, W1, b1,
                                          partials, countPartial, W1c, b1c);
    mlp_kernel<<<NROWPAIRS, 256, 0, stream>>>(stacks, valid, W1c, b1c,
                                              W2, b2, out);
}